// Round 5
// baseline (1380.996 us; speedup 1.0000x reference)
//
#include <hip/hip_runtime.h>
#include <math.h>

#define T_ 128

// ws offsets (floats) — layouts identical to round 4
#define OFF_M2      0         // [256][256]
#define OFF_WCOMBT  65536     // [128][1280]
#define OFF_BIAS    229376    // [1280]
#define OFF_WCT     230656    // [256][128]
#define OFF_XG2     263424    // [128 t][4 g][32 cb][32 lc][8 b]
#define OFF_BX2     4457728   // [128 t][4 g][256 col][8 b]
#define OFF_HSEQ    5506304   // [128 t][4 g][8 b][256]
#define OFF_HCSEQ   6554880   // [128 t][4 g][8 b][256]

#define SENTB 0xFFFFFFFFu

__device__ __forceinline__ float sigm_f(float x) { return 1.0f / (1.0f + __expf(-x)); }
__device__ __forceinline__ float tanh_f(float x) { return 1.0f - 2.0f / (__expf(2.0f * x) + 1.0f); }

__device__ __forceinline__ unsigned long long aload_u64(const unsigned long long* p) {
  return __hip_atomic_load(p, __ATOMIC_RELAXED, __HIP_MEMORY_SCOPE_AGENT);
}
__device__ __forceinline__ void astore_f(float* p, float v) {
  __hip_atomic_store(p, v, __ATOMIC_RELAXED, __HIP_MEMORY_SCOPE_AGENT);
}

// ---------------- pack: WcombT, bias, W_C^T ----------------
__global__ __launch_bounds__(256) void pack_kernel(
    const float* __restrict__ W_ih, const float* __restrict__ W_B,
    const float* __restrict__ b_ih, const float* __restrict__ b_hh,
    const float* __restrict__ b_B,  const float* __restrict__ W_C,
    float* __restrict__ ws) {
  int idx = blockIdx.x * 256 + threadIdx.x;
  if (idx < 163840) {  // WcombT[k][c]
    int k = idx / 1280, c = idx - k * 1280;
    ws[OFF_WCOMBT + idx] = (c < 1024) ? W_ih[c * 128 + k] : W_B[(c - 1024) * 128 + k];
    return;
  }
  idx -= 163840;
  if (idx < 1280) {
    ws[OFF_BIAS + idx] = (idx < 1024) ? (b_ih[idx] + b_hh[idx]) : b_B[idx - 1024];
    return;
  }
  idx -= 1280;
  if (idx < 32768) {  // W_CT[k][o]
    int k = idx >> 7, o = idx & 127;
    ws[OFF_WCT + idx] = W_C[o * 256 + k];
  }
}

// ---------------- M2 = (W_A D)(W_A D), D = diag(1/tau) ----------------
__global__ __launch_bounds__(256) void m2_kernel(
    const float* __restrict__ W_A, const float* __restrict__ tau,
    float* __restrict__ M2) {
  __shared__ float adrow[256];
  const int i = blockIdx.x, k = threadIdx.x;
  const float itk = 1.0f / tau[k];
  adrow[k] = W_A[i * 256 + k] * itk;
  __syncthreads();
  float s = 0.f;
#pragma unroll 8
  for (int m = 0; m < 256; ++m)
    s = fmaf(adrow[m], W_A[m * 256 + k], s);
  M2[i * 256 + k] = s * itk;
}

// ---------------- xg/Bx precompute, recur-native layout ----------------
__global__ __launch_bounds__(256) void xgt_kernel(
    const float* __restrict__ x, const float* __restrict__ WT,
    const float* __restrict__ bias, float* __restrict__ xg2,
    float* __restrict__ bx2) {
  __shared__ float xs[8 * 128];
  const int tid = threadIdx.x;
  const int rt = blockIdx.x, ct = blockIdx.y;
  ((float4*)xs)[tid] = ((const float4*)(x + rt * 1024))[tid];
  __syncthreads();
  const int r = tid >> 5, cg = tid & 31;
  const int c0 = ct * 256 + cg * 8;
  const float4* b4 = (const float4*)(bias + c0);
  float4 bA = b4[0], bB = b4[1];
  float a[8] = {bA.x, bA.y, bA.z, bA.w, bB.x, bB.y, bB.z, bB.w};
  const float4* xr4 = (const float4*)(xs + r * 128);
#pragma unroll 4
  for (int k4 = 0; k4 < 32; ++k4) {
    float4 xv = xr4[k4];
#define STEPB(kk, comp)                                                      \
    {                                                                        \
      const float4* w = (const float4*)(WT + (k4 * 4 + kk) * 1280 + c0);     \
      float4 wA = w[0], wB = w[1];                                           \
      a[0] = fmaf(wA.x, comp, a[0]); a[1] = fmaf(wA.y, comp, a[1]);          \
      a[2] = fmaf(wA.z, comp, a[2]); a[3] = fmaf(wA.w, comp, a[3]);          \
      a[4] = fmaf(wB.x, comp, a[4]); a[5] = fmaf(wB.y, comp, a[5]);          \
      a[6] = fmaf(wB.z, comp, a[6]); a[7] = fmaf(wB.w, comp, a[7]);          \
    }
    STEPB(0, xv.x) STEPB(1, xv.y) STEPB(2, xv.z) STEPB(3, xv.w)
#undef STEPB
  }
  const int row = rt * 8 + r;          // = b*128 + t
  const int b = row >> 7, t = row & 127;
  const int g = b >> 3, bl = b & 7;
  if (ct < 4) {
    const size_t base = ((size_t)((t * 4 + g) * 32 + cg)) * 256 + ct * 64 + bl;
#pragma unroll
    for (int i = 0; i < 8; ++i) xg2[base + i * 8] = a[i];
  } else {
    const size_t base = ((size_t)(t * 4 + g) * 256 + cg * 8) * 8 + bl;
#pragma unroll
    for (int i = 0; i < 8; ++i) bx2[base + i * 8] = a[i];
  }
}

// ---------------- recurrence: 64 blocks = 2 sets x 32 col-blocks, G=2 rotation ----
__global__ __launch_bounds__(256) void recur4_kernel(
    const float* __restrict__ ts_all, const float* __restrict__ tau,
    const float* __restrict__ sigma, const float* __restrict__ W_hh,
    const float* __restrict__ W_A, const float* __restrict__ M2,
    const float* __restrict__ xg2, const float* __restrict__ bx2,
    float* __restrict__ hseq, float* __restrict__ hcseq) {
  const int set = blockIdx.x >> 5, cb = blockIdx.x & 31;
  const int tid = threadIdx.x;

  // ---- gates weights: cg=tid&15 -> rows {cg, cg+16}; kq=tid>>4 -> 16 k ----
  const int cg = tid & 15, kq = tid >> 4;
  float wg[2][16];
#pragma unroll
  for (int c = 0; c < 2; ++c) {
    const int lc = cg + 16 * c;
    const int grow = (lc >> 3) * 256 + 8 * cb + (lc & 7);
    const float4* src = (const float4*)(W_hh + grow * 256 + kq * 16);
#pragma unroll
    for (int k4 = 0; k4 < 4; ++k4) {
      float4 v = src[k4];
      wg[c][4 * k4 + 0] = v.x; wg[c][4 * k4 + 1] = v.y;
      wg[c][4 * k4 + 2] = v.z; wg[c][4 * k4 + 3] = v.w;
    }
  }
  // ---- cfc weights: wv=tid>>6 rows {2wv,2wv+1}; kq6=tid&63 ----
  const int wv = tid >> 6, kq6 = tid & 63;
  float wcA[2][8], wc3[2][4];
#pragma unroll
  for (int r = 0; r < 2; ++r) {
    const int ci = 8 * cb + 2 * wv + r;
    const float it_i = 1.0f / tau[ci];
#pragma unroll
    for (int j = 0; j < 4; ++j)
#pragma unroll
      for (int e = 0; e < 2; ++e) {
        const int kp = 2 * kq6 + 128 * j + e;  // [0,512)
        wcA[r][2 * j + e] = (kp < 256) ? W_A[ci * 256 + kp] / tau[kp]
                                       : W_A[ci * 256 + (kp - 256)] * it_i;
      }
#pragma unroll
    for (int j = 0; j < 2; ++j)
#pragma unroll
      for (int e = 0; e < 2; ++e) {
        const int kp = 2 * kq6 + 128 * j + e;  // [0,256)
        wc3[r][2 * j + e] = 0.5f * M2[ci * 256 + kp];
      }
  }
  const float itau_comb = 1.0f / tau[8 * cb + ((tid >> 3) & 7)];

  __shared__ float h_s[8][256];
  __shared__ float hc_s[8][256];
  __shared__ float q_s[8][512];       // [q1 256 | q2 256]
  __shared__ float xg_s[256];
  __shared__ float gdot_s[256];
  __shared__ float redg[4256];        // kq*264 + col*9 + b  (col = cg+16c)
  __shared__ float redc[4][4][2][8];  // [wv][kqh][r][b]
  __shared__ float cst_s[2][64];
  __shared__ float isig_s[256];
  __shared__ float ts_s[8];
  isig_s[tid] = 1.0f / sigma[tid];
  if (tid < 128) cst_s[tid >> 6][tid & 63] = 0.f;
  __syncthreads();

  const unsigned long long* hsq  = (const unsigned long long*)hseq;
  const unsigned long long* hcsq = (const unsigned long long*)hcseq;

  // prologue prefetch for phase 0 (t=0, gi=0)
  unsigned long long nhv[4] = {0, 0, 0, 0}, ncv[4] = {0, 0, 0, 0};
  float nxg, nbx;
  {
    const int g0 = set * 2;
    nxg = xg2[((size_t)((0 * 4 + g0) * 32 + cb)) * 256 + tid];
    nbx = (tid < 64) ? bx2[((size_t)(0 * 4 + g0) * 256 + 8 * cb) * 8 + tid] : 0.f;
  }

  for (int p = 0; p < 2 * T_; ++p) {
    const int t = p >> 1, gi = p & 1, g = set * 2 + gi;
    // ======== A: stage state + build q (consume prefetch) ========
    xg_s[tid] = nxg;
    const float bxv = nbx;
    if (tid < 8) ts_s[tid] = ts_all[(g * 8 + tid) * T_ + t];
    if (t == 0) {
      const float2 z = make_float2(0.f, 0.f);
#pragma unroll
      for (int v = 0; v < 4; ++v) {
        const int flat = v * 256 + tid, b = flat >> 7, k2 = flat & 127;
        ((float2*)&h_s[b][0])[k2] = z;
        ((float2*)&hc_s[b][0])[k2] = z;
        float2* qrow = (float2*)&q_s[b][0];
        qrow[k2] = z; qrow[128 + k2] = z;
      }
    } else {
      const unsigned long long* hp  = hsq  + (size_t)((t - 1) * 4 + g) * 1024;
      const unsigned long long* hcp = hcsq + (size_t)((t - 1) * 4 + g) * 1024;
      bool again = true;
      while (again) {
        again = false;
#pragma unroll
        for (int v = 0; v < 4; ++v) {
          if ((unsigned)nhv[v] == SENTB || (unsigned)(nhv[v] >> 32) == SENTB) {
            nhv[v] = aload_u64(hp + v * 256 + tid); again = true;
          }
          if ((unsigned)ncv[v] == SENTB || (unsigned)(ncv[v] >> 32) == SENTB) {
            ncv[v] = aload_u64(hcp + v * 256 + tid); again = true;
          }
        }
      }
#pragma unroll
      for (int v = 0; v < 4; ++v) {
        const int flat = v * 256 + tid, b = flat >> 7, k2 = flat & 127;
        union { unsigned long long u; float2 f; } H, C;
        H.u = nhv[v]; C.u = ncv[v];
        ((float2*)&h_s[b][0])[k2] = H.f;
        ((float2*)&hc_s[b][0])[k2] = C.f;
        const float tsb = ts_all[(g * 8 + b) * T_ + t];
        const float2 isg = ((const float2*)isig_s)[k2];
        float2* qrow = (float2*)&q_s[b][0];
        qrow[k2]       = make_float2(tsb * C.f.x, tsb * C.f.y);
        qrow[128 + k2] = make_float2(tsb * tanh_f(C.f.x * isg.x),
                                     tsb * tanh_f(C.f.y * isg.y));
      }
    }
    __syncthreads();

    // ======== issue prefetch for phase p+1 (fire loads, consume next A) ========
    if (p + 1 < 2 * T_) {
      const int np = p + 1, nt = np >> 1, ng = set * 2 + (np & 1);
      nxg = xg2[((size_t)((nt * 4 + ng) * 32 + cb)) * 256 + tid];
      nbx = (tid < 64) ? bx2[((size_t)(nt * 4 + ng) * 256 + 8 * cb) * 8 + tid] : 0.f;
      if (nt >= 1) {
        const unsigned long long* hp  = hsq  + (size_t)((nt - 1) * 4 + ng) * 1024;
        const unsigned long long* hcp = hcsq + (size_t)((nt - 1) * 4 + ng) * 1024;
#pragma unroll
        for (int v = 0; v < 4; ++v) {
          nhv[v] = aload_u64(hp + v * 256 + tid);
          ncv[v] = aload_u64(hcp + v * 256 + tid);
        }
      }
    }

    // ======== B: matvecs + reductions ========
    // gates: acc[c][b] over k in [16kq, 16kq+16)
    float accg[2][8];
#pragma unroll
    for (int b = 0; b < 8; ++b) {
      const float4* h4p = (const float4*)&h_s[b][kq << 4];
      const float4 x0 = h4p[0], x1 = h4p[1], x2 = h4p[2], x3 = h4p[3];
#pragma unroll
      for (int c = 0; c < 2; ++c) {
        float s = wg[c][0] * x0.x;
        s = fmaf(wg[c][1],  x0.y, s); s = fmaf(wg[c][2],  x0.z, s);
        s = fmaf(wg[c][3],  x0.w, s); s = fmaf(wg[c][4],  x1.x, s);
        s = fmaf(wg[c][5],  x1.y, s); s = fmaf(wg[c][6],  x1.z, s);
        s = fmaf(wg[c][7],  x1.w, s); s = fmaf(wg[c][8],  x2.x, s);
        s = fmaf(wg[c][9],  x2.y, s); s = fmaf(wg[c][10], x2.z, s);
        s = fmaf(wg[c][11], x2.w, s); s = fmaf(wg[c][12], x3.x, s);
        s = fmaf(wg[c][13], x3.y, s); s = fmaf(wg[c][14], x3.z, s);
        s = fmaf(wg[c][15], x3.w, s);
        accg[c][b] = s;
      }
    }
#pragma unroll
    for (int c = 0; c < 2; ++c) {
      const int col = cg + 16 * c;
#pragma unroll
      for (int b = 0; b < 8; ++b)
        redg[kq * 264 + col * 9 + b] = accg[c][b];
    }
    // cfc: accA over [0,512) (q1,q2), acc3 over [0,256) (q1); dot = accA + ts*acc3
    float accc[2][8], acc3[2][8];
#pragma unroll
    for (int r = 0; r < 2; ++r)
#pragma unroll
      for (int b = 0; b < 8; ++b) { accc[r][b] = 0.f; acc3[r][b] = 0.f; }
#pragma unroll
    for (int b = 0; b < 8; ++b) {
      const float2* q2p = (const float2*)&q_s[b][0];
      const float2 qv0 = q2p[kq6];
      const float2 qv1 = q2p[kq6 + 64];
      const float2 qv2 = q2p[kq6 + 128];
      const float2 qv3 = q2p[kq6 + 192];
#pragma unroll
      for (int r = 0; r < 2; ++r) {
        float s = wcA[r][0] * qv0.x;
        s = fmaf(wcA[r][1], qv0.y, s);
        s = fmaf(wcA[r][2], qv1.x, s); s = fmaf(wcA[r][3], qv1.y, s);
        s = fmaf(wcA[r][4], qv2.x, s); s = fmaf(wcA[r][5], qv2.y, s);
        s = fmaf(wcA[r][6], qv3.x, s); s = fmaf(wcA[r][7], qv3.y, s);
        accc[r][b] = s;
        float s3 = wc3[r][0] * qv0.x;
        s3 = fmaf(wc3[r][1], qv0.y, s3);
        s3 = fmaf(wc3[r][2], qv1.x, s3); s3 = fmaf(wc3[r][3], qv1.y, s3);
        acc3[r][b] = s3;
      }
    }
    // per-lane ts fold, then DPP xor(1,2,4,8) reduce within 16-lane groups
#pragma unroll
    for (int r = 0; r < 2; ++r)
#pragma unroll
      for (int b = 0; b < 8; ++b) {
        float s = fmaf(ts_s[b], acc3[r][b], accc[r][b]);
        s += __shfl_xor(s, 1); s += __shfl_xor(s, 2);
        s += __shfl_xor(s, 4); s += __shfl_xor(s, 8);
        accc[r][b] = s;
      }
    if ((kq6 & 15) == 0) {
      const int kqh = kq6 >> 4;
#pragma unroll
      for (int r = 0; r < 2; ++r)
#pragma unroll
        for (int b = 0; b < 8; ++b)
          redc[wv][kqh][r][b] = accc[r][b];
    }
    __syncthreads();

    // ======== gates final sum (all 256 threads, slot = col*8+b = tid) ========
    {
      const int col = tid >> 3, b = tid & 7;
      float s = xg_s[tid];
#pragma unroll
      for (int k = 0; k < 16; ++k)
        s += redg[k * 264 + col * 9 + b];
      gdot_s[tid] = s;
    }
    __syncthreads();

    // ======== C: elementwise + stores (wave 0) ========
    if (tid < 64) {
      const int b = tid & 7, jj = tid >> 3;
      const float i_ = sigm_f(gdot_s[tid]);
      const float f_ = sigm_f(gdot_s[64 + tid]);
      const float g_ = tanh_f(gdot_s[128 + tid]);
      const float o_ = sigm_f(gdot_s[192 + tid]);
      const float cn = fmaf(f_, cst_s[gi][tid], i_ * g_);
      cst_s[gi][tid] = cn;
      const float ht = o_ * tanh_f(cn);
      const int rw = jj >> 1, rr = jj & 1;
      const float dot = redc[rw][0][rr][b] + redc[rw][1][rr][b] +
                        redc[rw][2][rr][b] + redc[rw][3][rr][b];
      const float hcold = hc_s[b][8 * cb + jj];
      const float tsb = ts_s[b];
      const float hn = hcold + dot + tsb * bxv * itau_comb + ht;
      const int col = 8 * cb + jj;
      astore_f(hseq  + (size_t)(t * 4 + g) * 2048 + b * 256 + col, ht);
      astore_f(hcseq + (size_t)(t * 4 + g) * 2048 + b * 256 + col, hn);
    }
    __syncthreads();
  }
}

// ---------------- y = hc @ W_C^T + b_C (reads hcseq [t][g][b][256]) ----------------
__global__ __launch_bounds__(256) void out_kernel(
    const float* __restrict__ hc, const float* __restrict__ WCT,
    const float* __restrict__ bC, float* __restrict__ y) {
  __shared__ float hs[16 * 256];
  const int tid = threadIdx.x;
#pragma unroll
  for (int v = 0; v < 4; ++v) {
    const int flat = v * 256 + tid;
    const int r = flat >> 6, f4 = flat & 63;
    const int row = blockIdx.x * 16 + r;   // = b*128 + t
    const int b = row >> 7, t = row & 127;
    ((float4*)hs)[flat] = ((const float4*)(hc + (size_t)(t * 32 + b) * 256))[f4];
  }
  __syncthreads();
  const int r = tid >> 4, cgg = tid & 15;
  const int c0 = cgg * 8;
  const float4* b4 = (const float4*)(bC + c0);
  float4 bA = b4[0], bB = b4[1];
  float a0 = bA.x, a1 = bA.y, a2 = bA.z, a3 = bA.w;
  float a4 = bB.x, a5 = bB.y, a6 = bB.z, a7 = bB.w;
  const float4* hr4 = (const float4*)(hs + r * 256);
#pragma unroll 4
  for (int k4 = 0; k4 < 64; ++k4) {
    float4 hv = hr4[k4];
#define STEPD(kk, comp)                                                     \
    {                                                                       \
      const float4* w = (const float4*)(WCT + (k4 * 4 + kk) * 128 + c0);    \
      float4 wA = w[0], wB = w[1];                                          \
      a0 = fmaf(wA.x, comp, a0); a1 = fmaf(wA.y, comp, a1);                 \
      a2 = fmaf(wA.z, comp, a2); a3 = fmaf(wA.w, comp, a3);                 \
      a4 = fmaf(wB.x, comp, a4); a5 = fmaf(wB.y, comp, a5);                 \
      a6 = fmaf(wB.z, comp, a6); a7 = fmaf(wB.w, comp, a7);                 \
    }
    STEPD(0, hv.x) STEPD(1, hv.y) STEPD(2, hv.z) STEPD(3, hv.w)
#undef STEPD
  }
  const int row = blockIdx.x * 16 + r;
  float4* dst = (float4*)(y + (size_t)row * 128 + c0);
  dst[0] = make_float4(a0, a1, a2, a3);
  dst[1] = make_float4(a4, a5, a6, a7);
}

extern "C" void kernel_launch(void* const* d_in, const int* in_sizes, int n_in,
                              void* d_out, int out_size, void* d_ws, size_t ws_size,
                              hipStream_t stream) {
  const float* x     = (const float*)d_in[0];
  const float* tspan = (const float*)d_in[1];
  const float* tau   = (const float*)d_in[2];
  const float* sigma = (const float*)d_in[3];
  const float* W_A   = (const float*)d_in[4];
  const float* W_B   = (const float*)d_in[5];
  const float* b_B   = (const float*)d_in[6];
  const float* W_C   = (const float*)d_in[7];
  const float* b_C   = (const float*)d_in[8];
  const float* W_ih  = (const float*)d_in[9];
  const float* W_hh  = (const float*)d_in[10];
  const float* b_ih  = (const float*)d_in[11];
  const float* b_hh  = (const float*)d_in[12];
  float* ws = (float*)d_ws;
  float* y = (float*)d_out;

  // sentinel-fill hseq+hcseq (0xFF bytes == SENTB dwords), 8 MB
  hipMemsetAsync(ws + OFF_HSEQ, 0xFF, (size_t)2 * 1048576 * sizeof(float), stream);
  pack_kernel<<<774, 256, 0, stream>>>(W_ih, W_B, b_ih, b_hh, b_B, W_C, ws);
  m2_kernel<<<256, 256, 0, stream>>>(W_A, tau, ws + OFF_M2);
  xgt_kernel<<<dim3(512, 5), 256, 0, stream>>>(x, ws + OFF_WCOMBT, ws + OFF_BIAS,
                                               ws + OFF_XG2, ws + OFF_BX2);
  recur4_kernel<<<64, 256, 0, stream>>>(
      tspan, tau, sigma, W_hh, W_A, ws + OFF_M2, ws + OFF_XG2, ws + OFF_BX2,
      ws + OFF_HSEQ, ws + OFF_HCSEQ);
  out_kernel<<<256, 256, 0, stream>>>(ws + OFF_HCSEQ, ws + OFF_WCT, b_C, y);
}

// Round 8
// 789.781 us; speedup vs baseline: 1.7486x; 1.7486x over previous
//
#include <hip/hip_runtime.h>
#include <math.h>

#define T_ 128
#define NG 4
#define BPG 8

// ws offsets (floats) — layouts identical to round 4
#define OFF_M2      0         // [256][256]
#define OFF_WCOMBT  65536     // [128][1280]
#define OFF_BIAS    229376    // [1280]
#define OFF_WCT     230656    // [256][128]
#define OFF_XG2     263424    // [128 t][4 g][32 cb][32 lc][8 b]
#define OFF_BX2     4457728   // [128 t][4 g][256 col][8 b]
#define OFF_HSEQ    5506304   // [128 t][4 g][8 b][256]
#define OFF_HCSEQ   6554880   // [128 t][4 g][8 b][256]

#define SENTB 0xFFFFFFFFu

__device__ __forceinline__ float sigm_f(float x) { return 1.0f / (1.0f + __expf(-x)); }
__device__ __forceinline__ float tanh_f(float x) { return 1.0f - 2.0f / (__expf(2.0f * x) + 1.0f); }

__device__ __forceinline__ unsigned long long aload_u64(const unsigned long long* p) {
  return __hip_atomic_load(p, __ATOMIC_RELAXED, __HIP_MEMORY_SCOPE_AGENT);
}
__device__ __forceinline__ void astore_f(float* p, float v) {
  __hip_atomic_store(p, v, __ATOMIC_RELAXED, __HIP_MEMORY_SCOPE_AGENT);
}

// ---------------- pack: WcombT, bias, W_C^T ----------------
__global__ __launch_bounds__(256) void pack_kernel(
    const float* __restrict__ W_ih, const float* __restrict__ W_B,
    const float* __restrict__ b_ih, const float* __restrict__ b_hh,
    const float* __restrict__ b_B,  const float* __restrict__ W_C,
    float* __restrict__ ws) {
  int idx = blockIdx.x * 256 + threadIdx.x;
  if (idx < 163840) {  // WcombT[k][c]
    int k = idx / 1280, c = idx - k * 1280;
    ws[OFF_WCOMBT + idx] = (c < 1024) ? W_ih[c * 128 + k] : W_B[(c - 1024) * 128 + k];
    return;
  }
  idx -= 163840;
  if (idx < 1280) {
    ws[OFF_BIAS + idx] = (idx < 1024) ? (b_ih[idx] + b_hh[idx]) : b_B[idx - 1024];
    return;
  }
  idx -= 1280;
  if (idx < 32768) {  // W_CT[k][o]
    int k = idx >> 7, o = idx & 127;
    ws[OFF_WCT + idx] = W_C[o * 256 + k];
  }
}

// ---------------- M2 = (W_A D)(W_A D), D = diag(1/tau) ----------------
__global__ __launch_bounds__(256) void m2_kernel(
    const float* __restrict__ W_A, const float* __restrict__ tau,
    float* __restrict__ M2) {
  __shared__ float adrow[256];
  const int i = blockIdx.x, k = threadIdx.x;
  const float itk = 1.0f / tau[k];
  adrow[k] = W_A[i * 256 + k] * itk;
  __syncthreads();
  float s = 0.f;
#pragma unroll 8
  for (int m = 0; m < 256; ++m)
    s = fmaf(adrow[m], W_A[m * 256 + k], s);
  M2[i * 256 + k] = s * itk;
}

// ---------------- xg/Bx precompute, recur-native layout (R4 verbatim) ----------------
__global__ __launch_bounds__(256) void xgt_kernel(
    const float* __restrict__ x, const float* __restrict__ WT,
    const float* __restrict__ bias, float* __restrict__ xg2,
    float* __restrict__ bx2) {
  __shared__ float xs[8 * 128];
  const int tid = threadIdx.x;
  const int rt = blockIdx.x, ct = blockIdx.y;
  ((float4*)xs)[tid] = ((const float4*)(x + rt * 1024))[tid];
  __syncthreads();
  const int r = tid >> 5, cg = tid & 31;
  const int c0 = ct * 256 + cg * 8;
  const float4* b4 = (const float4*)(bias + c0);
  float4 bA = b4[0], bB = b4[1];
  float a[8] = {bA.x, bA.y, bA.z, bA.w, bB.x, bB.y, bB.z, bB.w};
  const float4* xr4 = (const float4*)(xs + r * 128);
#pragma unroll 4
  for (int k4 = 0; k4 < 32; ++k4) {
    float4 xv = xr4[k4];
#define STEPB(kk, comp)                                                      \
    {                                                                        \
      const float4* w = (const float4*)(WT + (k4 * 4 + kk) * 1280 + c0);     \
      float4 wA = w[0], wB = w[1];                                           \
      a[0] = fmaf(wA.x, comp, a[0]); a[1] = fmaf(wA.y, comp, a[1]);          \
      a[2] = fmaf(wA.z, comp, a[2]); a[3] = fmaf(wA.w, comp, a[3]);          \
      a[4] = fmaf(wB.x, comp, a[4]); a[5] = fmaf(wB.y, comp, a[5]);          \
      a[6] = fmaf(wB.z, comp, a[6]); a[7] = fmaf(wB.w, comp, a[7]);          \
    }
    STEPB(0, xv.x) STEPB(1, xv.y) STEPB(2, xv.z) STEPB(3, xv.w)
#undef STEPB
  }
  const int row = rt * 8 + r;          // = b*128 + t
  const int b = row >> 7, t = row & 127;
  const int g = b >> 3, bl = b & 7;
  if (ct < 4) {
    const size_t base = ((size_t)((t * 4 + g) * 32 + cg)) * 256 + ct * 64 + bl;
#pragma unroll
    for (int i = 0; i < 8; ++i) xg2[base + i * 8] = a[i];
  } else {
    const size_t base = ((size_t)(t * 4 + g) * 256 + cg * 8) * 8 + bl;
#pragma unroll
    for (int i = 0; i < 8; ++i) bx2[base + i * 8] = a[i];
  }
}

// ---------------- recurrence: 128 blocks, sentinel dataflow, batched retry ----------
__global__ __launch_bounds__(256) void recur8_kernel(
    const float* __restrict__ ts_all, const float* __restrict__ tau,
    const float* __restrict__ sigma, const float* __restrict__ W_hh,
    const float* __restrict__ W_A, const float* __restrict__ M2,
    const float* __restrict__ xg2, const float* __restrict__ bx2,
    float* __restrict__ hseq, float* __restrict__ hcseq) {
  const int g = blockIdx.x >> 5, cb = blockIdx.x & 31;
  const int tid = threadIdx.x;

  // ---- gates weights: cg = tid&15 (LOW bits: column group -> broadcast h reads),
  //      kq = tid>>4 (HIGH bits: k-chunk of 16) ----
  const int cg = tid & 15, kq = tid >> 4;
  float wg[2][16];
#pragma unroll
  for (int c = 0; c < 2; ++c) {
    const int lc = cg + 16 * c;                          // lc in [0,32)
    const int grow = (lc >> 3) * 256 + 8 * cb + (lc & 7);
    const float4* src = (const float4*)(W_hh + grow * 256 + kq * 16);
#pragma unroll
    for (int k4 = 0; k4 < 4; ++k4) {
      float4 v = src[k4];
      wg[c][4 * k4 + 0] = v.x; wg[c][4 * k4 + 1] = v.y;
      wg[c][4 * k4 + 2] = v.z; wg[c][4 * k4 + 3] = v.w;
    }
  }
  // ---- cfc weights (R4 verbatim): wave wv rows {2wv,2wv+1}; k' = 2*kq6 + 128j + e ----
  const int wv = tid >> 6, kq6 = tid & 63;
  float wc[2][12];
#pragma unroll
  for (int r = 0; r < 2; ++r) {
    const int ci = 8 * cb + 2 * wv + r;
    const float it_i = 1.0f / tau[ci];
#pragma unroll
    for (int j = 0; j < 6; ++j) {
#pragma unroll
      for (int e = 0; e < 2; ++e) {
        const int kp = 2 * kq6 + 128 * j + e;
        float v;
        if (kp < 256)      v = W_A[ci * 256 + kp] / tau[kp];
        else if (kp < 512) v = W_A[ci * 256 + (kp - 256)] * it_i;
        else               v = 0.5f * M2[ci * 256 + (kp - 512)];
        wc[r][2 * j + e] = v;
      }
    }
  }
  const float itau_comb = 1.0f / tau[8 * cb + ((tid >> 3) & 7)];

  __shared__ float h_s[8][256];
  __shared__ float hc_s[8][256];
  __shared__ float q_s[8][768];
  __shared__ float xg_s[256];
  __shared__ float gdot_s[256];
  __shared__ float redg[16 * 297];    // kq*297 + col*9 + b  (col in [0,32), kq-skew 297)
  __shared__ float redc[4][4][2][8];  // [wv][kqh][r][b]
  __shared__ float cst_s[64];
  __shared__ float isig_s[256];
  __shared__ float ts_s[8];
  isig_s[tid] = 1.0f / sigma[tid];
  if (tid < 64) cst_s[tid] = 0.f;
  __syncthreads();

  const unsigned long long* hsq  = (const unsigned long long*)hseq;
  const unsigned long long* hcsq = (const unsigned long long*)hcseq;

  for (int t = 0; t < T_; ++t) {
    // ======== Stage A: prefetch + stage state + build q ========
    xg_s[tid] = xg2[((size_t)((t * 4 + g) * 32 + cb)) * 256 + tid];
    float bxv = 0.f;
    if (tid < 64)
      bxv = bx2[((size_t)(t * 4 + g) * 256 + 8 * cb) * 8 + tid];
    if (tid < 8) ts_s[tid] = ts_all[(g * 8 + tid) * T_ + t];

    if (t == 0) {
      const float2 z = make_float2(0.f, 0.f);
#pragma unroll
      for (int v = 0; v < 4; ++v) {
        const int flat = v * 256 + tid, b = flat >> 7, k2 = flat & 127;
        ((float2*)&h_s[b][0])[k2] = z;
        ((float2*)&hc_s[b][0])[k2] = z;
        float2* qrow = (float2*)&q_s[b][0];
        qrow[k2] = z; qrow[128 + k2] = z; qrow[256 + k2] = z;
      }
    } else {
      const unsigned long long* hp  = hsq  + (size_t)((t - 1) * 4 + g) * 1024 + tid;
      const unsigned long long* hcp = hcsq + (size_t)((t - 1) * 4 + g) * 1024 + tid;
      unsigned long long hv[4], cv[4];
      // batched retry: 8 independent loads -> one wait -> check; divergent exit
      bool again;
      do {
        again = false;
#pragma unroll
        for (int v = 0; v < 4; ++v) {
          hv[v] = aload_u64(hp + v * 256);
          cv[v] = aload_u64(hcp + v * 256);
        }
#pragma unroll
        for (int v = 0; v < 4; ++v) {
          if ((unsigned)hv[v] == SENTB || (unsigned)(hv[v] >> 32) == SENTB ||
              (unsigned)cv[v] == SENTB || (unsigned)(cv[v] >> 32) == SENTB)
            again = true;
        }
      } while (again);
#pragma unroll
      for (int v = 0; v < 4; ++v) {
        const int flat = v * 256 + tid, b = flat >> 7, k2 = flat & 127;
        union { unsigned long long u; float2 f; } H, C;
        H.u = hv[v]; C.u = cv[v];
        ((float2*)&h_s[b][0])[k2] = H.f;
        ((float2*)&hc_s[b][0])[k2] = C.f;
        const float tsb = ts_all[(g * 8 + b) * T_ + t];
        const float2 isg = ((const float2*)isig_s)[k2];
        float2* qrow = (float2*)&q_s[b][0];
        float2 q0 = make_float2(tsb * C.f.x, tsb * C.f.y);
        qrow[k2] = q0;
        qrow[128 + k2] = make_float2(tsb * tanh_f(C.f.x * isg.x),
                                     tsb * tanh_f(C.f.y * isg.y));
        qrow[256 + k2] = make_float2(tsb * q0.x, tsb * q0.y);
      }
    }
    __syncthreads();

    // ======== Stage B: matvecs + reductions ========
    // gates: 16 lanes (same kq) broadcast-read the same h float4s -> conflict-free
    float accg[2][8];
#pragma unroll
    for (int b = 0; b < 8; ++b) {
      const float4* h4p = (const float4*)&h_s[b][kq << 4];
      const float4 x0 = h4p[0], x1 = h4p[1], x2 = h4p[2], x3 = h4p[3];
#pragma unroll
      for (int c = 0; c < 2; ++c) {
        float s = wg[c][0] * x0.x;
        s = fmaf(wg[c][1],  x0.y, s); s = fmaf(wg[c][2],  x0.z, s);
        s = fmaf(wg[c][3],  x0.w, s); s = fmaf(wg[c][4],  x1.x, s);
        s = fmaf(wg[c][5],  x1.y, s); s = fmaf(wg[c][6],  x1.z, s);
        s = fmaf(wg[c][7],  x1.w, s); s = fmaf(wg[c][8],  x2.x, s);
        s = fmaf(wg[c][9],  x2.y, s); s = fmaf(wg[c][10], x2.z, s);
        s = fmaf(wg[c][11], x2.w, s); s = fmaf(wg[c][12], x3.x, s);
        s = fmaf(wg[c][13], x3.y, s); s = fmaf(wg[c][14], x3.z, s);
        s = fmaf(wg[c][15], x3.w, s);
        accg[c][b] = s;
      }
    }
#pragma unroll
    for (int c = 0; c < 2; ++c) {
      const int col = cg + 16 * c;
#pragma unroll
      for (int b = 0; b < 8; ++b)
        redg[kq * 297 + col * 9 + b] = accg[c][b];
    }
    // cfc (R4 verbatim): stride-paired float2 q reads (2-way = free)
    float accc[2][8];
#pragma unroll
    for (int r = 0; r < 2; ++r)
#pragma unroll
      for (int b = 0; b < 8; ++b) accc[r][b] = 0.f;
#pragma unroll
    for (int b = 0; b < 8; ++b) {
      const float2* q2p = (const float2*)&q_s[b][0];
#pragma unroll
      for (int j = 0; j < 6; ++j) {
        const float2 qv = q2p[kq6 + 64 * j];
#pragma unroll
        for (int r = 0; r < 2; ++r) {
          accc[r][b] = fmaf(wc[r][2 * j],     qv.x, accc[r][b]);
          accc[r][b] = fmaf(wc[r][2 * j + 1], qv.y, accc[r][b]);
        }
      }
    }
#pragma unroll
    for (int r = 0; r < 2; ++r)
#pragma unroll
      for (int b = 0; b < 8; ++b) {
        float s = accc[r][b];
        s += __shfl_xor(s, 1); s += __shfl_xor(s, 2);
        s += __shfl_xor(s, 4); s += __shfl_xor(s, 8);
        accc[r][b] = s;
      }
    if ((kq6 & 15) == 0) {
      const int kqh = kq6 >> 4;
#pragma unroll
      for (int r = 0; r < 2; ++r)
#pragma unroll
        for (int b = 0; b < 8; ++b)
          redc[wv][kqh][r][b] = accc[r][b];
    }
    __syncthreads();

    // ======== gates final sum (thread tid: col = tid>>3, b = tid&7) ========
    {
      const int col = tid >> 3, b = tid & 7;
      float s = 0.f;
#pragma unroll
      for (int k = 0; k < 16; ++k)
        s += redg[k * 297 + col * 9 + b];
      gdot_s[tid] = s;
    }
    __syncthreads();

    // ======== Stage C: elementwise + stores (wave 0; b = tid&7, jj = tid>>3) ========
    if (tid < 64) {
      const int b = tid & 7, jj = tid >> 3;
      const float i_ = sigm_f(gdot_s[tid]       + xg_s[tid]);
      const float f_ = sigm_f(gdot_s[64 + tid]  + xg_s[64 + tid]);
      const float g_ = tanh_f(gdot_s[128 + tid] + xg_s[128 + tid]);
      const float o_ = sigm_f(gdot_s[192 + tid] + xg_s[192 + tid]);
      const float cn = fmaf(f_, cst_s[tid], i_ * g_);
      cst_s[tid] = cn;
      const float ht = o_ * tanh_f(cn);
      const int rw = jj >> 1, rr = jj & 1;
      const float dot = redc[rw][0][rr][b] + redc[rw][1][rr][b] +
                        redc[rw][2][rr][b] + redc[rw][3][rr][b];
      const float hcold = hc_s[b][8 * cb + jj];
      const float tsb = ts_s[b];
      const float hn = hcold + dot + tsb * bxv * itau_comb + ht;
      const int col = 8 * cb + jj;
      astore_f(hseq  + (size_t)(t * 4 + g) * 2048 + b * 256 + col, ht);
      astore_f(hcseq + (size_t)(t * 4 + g) * 2048 + b * 256 + col, hn);
    }
    __syncthreads();
  }
}

// ---------------- y = hc @ W_C^T + b_C (reads hcseq [t][g][b][256]) ----------------
__global__ __launch_bounds__(256) void out_kernel(
    const float* __restrict__ hc, const float* __restrict__ WCT,
    const float* __restrict__ bC, float* __restrict__ y) {
  __shared__ float hs[16 * 256];
  const int tid = threadIdx.x;
#pragma unroll
  for (int v = 0; v < 4; ++v) {
    const int flat = v * 256 + tid;
    const int r = flat >> 6, f4 = flat & 63;
    const int row = blockIdx.x * 16 + r;   // = b*128 + t
    const int b = row >> 7, t = row & 127;
    ((float4*)hs)[flat] = ((const float4*)(hc + (size_t)(t * 32 + b) * 256))[f4];
  }
  __syncthreads();
  const int r = tid >> 4, cgg = tid & 15;
  const int c0 = cgg * 8;
  const float4* b4 = (const float4*)(bC + c0);
  float4 bA = b4[0], bB = b4[1];
  float a0 = bA.x, a1 = bA.y, a2 = bA.z, a3 = bA.w;
  float a4 = bB.x, a5 = bB.y, a6 = bB.z, a7 = bB.w;
  const float4* hr4 = (const float4*)(hs + r * 256);
#pragma unroll 4
  for (int k4 = 0; k4 < 64; ++k4) {
    float4 hv = hr4[k4];
#define STEPD(kk, comp)                                                     \
    {                                                                       \
      const float4* w = (const float4*)(WCT + (k4 * 4 + kk) * 128 + c0);    \
      float4 wA = w[0], wB = w[1];                                          \
      a0 = fmaf(wA.x, comp, a0); a1 = fmaf(wA.y, comp, a1);                 \
      a2 = fmaf(wA.z, comp, a2); a3 = fmaf(wA.w, comp, a3);                 \
      a4 = fmaf(wB.x, comp, a4); a5 = fmaf(wB.y, comp, a5);                 \
      a6 = fmaf(wB.z, comp, a6); a7 = fmaf(wB.w, comp, a7);                 \
    }
    STEPD(0, hv.x) STEPD(1, hv.y) STEPD(2, hv.z) STEPD(3, hv.w)
#undef STEPD
  }
  const int row = blockIdx.x * 16 + r;
  float4* dst = (float4*)(y + (size_t)row * 128 + c0);
  dst[0] = make_float4(a0, a1, a2, a3);
  dst[1] = make_float4(a4, a5, a6, a7);
}

extern "C" void kernel_launch(void* const* d_in, const int* in_sizes, int n_in,
                              void* d_out, int out_size, void* d_ws, size_t ws_size,
                              hipStream_t stream) {
  const float* x     = (const float*)d_in[0];
  const float* tspan = (const float*)d_in[1];
  const float* tau   = (const float*)d_in[2];
  const float* sigma = (const float*)d_in[3];
  const float* W_A   = (const float*)d_in[4];
  const float* W_B   = (const float*)d_in[5];
  const float* b_B   = (const float*)d_in[6];
  const float* W_C   = (const float*)d_in[7];
  const float* b_C   = (const float*)d_in[8];
  const float* W_ih  = (const float*)d_in[9];
  const float* W_hh  = (const float*)d_in[10];
  const float* b_ih  = (const float*)d_in[11];
  const float* b_hh  = (const float*)d_in[12];
  float* ws = (float*)d_ws;
  float* y = (float*)d_out;

  // sentinel-fill hseq+hcseq (0xFF bytes == SENTB dwords), 8 MB
  hipMemsetAsync(ws + OFF_HSEQ, 0xFF, (size_t)2 * 1048576 * sizeof(float), stream);
  pack_kernel<<<774, 256, 0, stream>>>(W_ih, W_B, b_ih, b_hh, b_B, W_C, ws);
  m2_kernel<<<256, 256, 0, stream>>>(W_A, tau, ws + OFF_M2);
  xgt_kernel<<<dim3(512, 5), 256, 0, stream>>>(x, ws + OFF_WCOMBT, ws + OFF_BIAS,
                                               ws + OFF_XG2, ws + OFF_BX2);
  recur8_kernel<<<128, 256, 0, stream>>>(
      tspan, tau, sigma, W_hh, W_A, ws + OFF_M2, ws + OFF_XG2, ws + OFF_BX2,
      ws + OFF_HSEQ, ws + OFF_HCSEQ);
  out_kernel<<<256, 256, 0, stream>>>(ws + OFF_HCSEQ, ws + OFF_WCT, b_C, y);
}